// Round 1
// baseline (2856.603 us; speedup 1.0000x reference)
//
#include <hip/hip_runtime.h>
#include <cstdint>

#define B_   512
#define I_   2560
#define H_   512
#define E_   300
#define V_   8000
#define T_   16
#define G4H  2048
#define SOS_ 2

#define K0CAT 832    // 512 (h0) + 300 (emb) + 20 pad
#define K1CAT 1024   // 512 (h0) + 512 (h1)

__device__ __forceinline__ float sigmoidf_(float x) {
    return 1.0f / (1.0f + __expf(-x));
}

// ---------------------------------------------------------------------------
// Generic fp32 GEMM: C[M,N] = A[M,K] @ B[N,K]^T (+ bias1[n] + bias2[n] + Cadd[m,n])
// Grid: (M/64, N/64), block 256 threads, each thread 4x4 outputs. K % 16 == 0.
// ---------------------------------------------------------------------------
#define BM 64
#define BN 64
#define BK 16
#define LDSS 68   // padded stride: keeps float4 LDS reads 16B-aligned, conflicts <=2-way

__global__ __launch_bounds__(256)
void gemm_tn(const float* __restrict__ A, int lda,
             const float* __restrict__ Bw, int ldb,
             float* __restrict__ C, int ldc,
             int K,
             const float* __restrict__ bias1,
             const float* __restrict__ bias2,
             const float* __restrict__ Cadd, int ldadd)
{
    __shared__ float As[BK][LDSS];
    __shared__ float Bs[BK][LDSS];
    const int tid = threadIdx.x;
    const int bm = blockIdx.x * BM;
    const int bn = blockIdx.y * BN;
    const int tm = (tid >> 4) << 2;   // 0..60
    const int tn = (tid & 15) << 2;   // 0..60
    const int lrow = tid >> 2;        // 0..63
    const int lk   = (tid & 3) << 2;  // 0,4,8,12

    const float* Aload = A + (size_t)(bm + lrow) * lda + lk;
    const float* Bload = Bw + (size_t)(bn + lrow) * ldb + lk;

    float acc[4][4] = {};

    for (int k0 = 0; k0 < K; k0 += BK) {
        const float4 av = *reinterpret_cast<const float4*>(Aload + k0);
        const float4 bv = *reinterpret_cast<const float4*>(Bload + k0);
        __syncthreads();
        As[lk + 0][lrow] = av.x; As[lk + 1][lrow] = av.y;
        As[lk + 2][lrow] = av.z; As[lk + 3][lrow] = av.w;
        Bs[lk + 0][lrow] = bv.x; Bs[lk + 1][lrow] = bv.y;
        Bs[lk + 2][lrow] = bv.z; Bs[lk + 3][lrow] = bv.w;
        __syncthreads();
        #pragma unroll
        for (int kk = 0; kk < BK; ++kk) {
            const float4 a4 = *reinterpret_cast<const float4*>(&As[kk][tm]);
            const float4 b4 = *reinterpret_cast<const float4*>(&Bs[kk][tn]);
            const float aa[4] = {a4.x, a4.y, a4.z, a4.w};
            const float bb[4] = {b4.x, b4.y, b4.z, b4.w};
            #pragma unroll
            for (int i = 0; i < 4; ++i)
                #pragma unroll
                for (int j = 0; j < 4; ++j)
                    acc[i][j] = fmaf(aa[i], bb[j], acc[i][j]);
        }
    }

    #pragma unroll
    for (int i = 0; i < 4; ++i) {
        const int m = bm + tm + i;
        float vv[4];
        #pragma unroll
        for (int j = 0; j < 4; ++j) {
            float r = acc[i][j];
            if (bias1) r += bias1[bn + tn + j];
            if (bias2) r += bias2[bn + tn + j];
            vv[j] = r;
        }
        if (Cadd) {
            const float4 ca = *reinterpret_cast<const float4*>(Cadd + (size_t)m * ldadd + bn + tn);
            vv[0] += ca.x; vv[1] += ca.y; vv[2] += ca.z; vv[3] += ca.w;
        }
        *reinterpret_cast<float4*>(C + (size_t)m * ldc + bn + tn) =
            make_float4(vv[0], vv[1], vv[2], vv[3]);
    }
}

// ---------------------------------------------------------------------------
// Pack recurrent weights: W0cat[2048][832] = [W_hh0 | W_ih0[:, :300] | 0],
//                         W1cat[2048][1024] = [W_ih1 | W_hh1]
// ---------------------------------------------------------------------------
__global__ __launch_bounds__(256)
void pack_w(const float* __restrict__ W_hh0, const float* __restrict__ W_ih0,
            const float* __restrict__ W_ih1, const float* __restrict__ W_hh1,
            float* __restrict__ W0cat, float* __restrict__ W1cat)
{
    const int idx = blockIdx.x * 256 + threadIdx.x;
    const int N0 = G4H * K0CAT;
    if (idx < N0) {
        const int g = idx / K0CAT, k = idx % K0CAT;
        float v;
        if (k < 512)      v = W_hh0[(size_t)g * 512 + k];
        else if (k < 812) v = W_ih0[(size_t)g * 812 + (k - 512)];
        else              v = 0.0f;
        W0cat[idx] = v;
    } else {
        const int j = idx - N0;
        const int g = j / K1CAT, k = j % K1CAT;
        W1cat[j] = (k < 512) ? W_ih1[(size_t)g * 512 + k]
                             : W_hh1[(size_t)g * 512 + (k - 512)];
    }
}

// ---------------------------------------------------------------------------
// Init: A0[:, :512]=ctx, A0[:, 812:832]=0, A1[:, 512:]=ctx (h1 init), c0=c1=ccell
// ---------------------------------------------------------------------------
__global__ __launch_bounds__(256)
void init_state(const float* __restrict__ ctx, const float* __restrict__ ccell,
                float* __restrict__ A0, float* __restrict__ A1,
                float* __restrict__ c0, float* __restrict__ c1)
{
    const int idx = blockIdx.x * 256 + threadIdx.x;   // 0 .. 512*512-1
    const int b = idx >> 9, h = idx & 511;
    const float cv = ctx[idx];
    A0[(size_t)b * K0CAT + h] = cv;
    A1[(size_t)b * K1CAT + 512 + h] = cv;
    const float cc = ccell[idx];
    c0[idx] = cc;
    c1[idx] = cc;
    if (h < K0CAT - 812) A0[(size_t)b * K0CAT + 812 + h] = 0.0f;
}

// ---------------------------------------------------------------------------
// Per-step embedding gather into A0[:, 512:812]
// ---------------------------------------------------------------------------
__global__ __launch_bounds__(256)
void pack_emb(const float* __restrict__ emb, const int* __restrict__ target,
              float* __restrict__ A0, int t)
{
    const int idx = blockIdx.x * 256 + threadIdx.x;   // 0 .. 512*300-1
    const int b = idx / E_, e = idx % E_;
    const int w = (t == 0) ? SOS_ : target[b * T_ + (t - 1)];
    A0[(size_t)b * K0CAT + 512 + e] = emb[(size_t)w * E_ + e];
}

// ---------------------------------------------------------------------------
// LSTM cell layer 0: update c0, write h0 into A0[:, :512] and A1[:, :512]
// ---------------------------------------------------------------------------
__global__ __launch_bounds__(256)
void lstm_cell0(const float* __restrict__ gates, float* __restrict__ c0,
                float* __restrict__ A0, float* __restrict__ A1)
{
    const int idx = blockIdx.x * 256 + threadIdx.x;   // 0 .. 512*512-1
    const int b = idx >> 9, h = idx & 511;
    const float* gr = gates + (size_t)b * G4H;
    const float gi = gr[h], gf = gr[512 + h], gg = gr[1024 + h], go = gr[1536 + h];
    const float c = c0[idx];
    const float cn = sigmoidf_(gf) * c + sigmoidf_(gi) * tanhf(gg);
    const float hn = sigmoidf_(go) * tanhf(cn);
    c0[idx] = cn;
    A0[(size_t)b * K0CAT + h] = hn;
    A1[(size_t)b * K1CAT + h] = hn;
}

// ---------------------------------------------------------------------------
// LSTM cell layer 1: update c1, write h1 into A1[:, 512:] and hs[b*T+t]
// ---------------------------------------------------------------------------
__global__ __launch_bounds__(256)
void lstm_cell1(const float* __restrict__ gates, float* __restrict__ c1,
                float* __restrict__ A1, float* __restrict__ hs, int t)
{
    const int idx = blockIdx.x * 256 + threadIdx.x;
    const int b = idx >> 9, h = idx & 511;
    const float* gr = gates + (size_t)b * G4H;
    const float gi = gr[h], gf = gr[512 + h], gg = gr[1024 + h], go = gr[1536 + h];
    const float c = c1[idx];
    const float cn = sigmoidf_(gf) * c + sigmoidf_(gi) * tanhf(gg);
    const float hn = sigmoidf_(go) * tanhf(cn);
    c1[idx] = cn;
    A1[(size_t)b * K1CAT + 512 + h] = hn;
    hs[((size_t)b * T_ + t) * H_ + h] = hn;
}

// ---------------------------------------------------------------------------
extern "C" void kernel_launch(void* const* d_in, const int* in_sizes, int n_in,
                              void* d_out, int out_size, void* d_ws, size_t ws_size,
                              hipStream_t stream)
{
    const float* fused  = (const float*)d_in[0];
    const int*   target = (const int*)d_in[1];
    // d_in[2] = max_len (always 16)
    const float* emb    = (const float*)d_in[3];
    const float* W_in   = (const float*)d_in[4];
    const float* b_in   = (const float*)d_in[5];
    const float* W_cell = (const float*)d_in[6];
    const float* b_cell = (const float*)d_in[7];
    const float* W_ih0  = (const float*)d_in[8];
    const float* W_hh0  = (const float*)d_in[9];
    const float* b_ih0  = (const float*)d_in[10];
    const float* b_hh0  = (const float*)d_in[11];
    const float* W_ih1  = (const float*)d_in[12];
    const float* W_hh1  = (const float*)d_in[13];
    const float* b_ih1  = (const float*)d_in[14];
    const float* b_hh1  = (const float*)d_in[15];
    const float* W_out  = (const float*)d_in[16];
    const float* b_out  = (const float*)d_in[17];
    float* out = (float*)d_out;

    float* p = (float*)d_ws;
    float* ctx   = p; p += (size_t)B_ * H_;       // 512x512
    float* ccell = p; p += (size_t)B_ * H_;       // 512x512
    float* ctxg  = p; p += (size_t)B_ * G4H;      // 512x2048
    float* W0cat = p; p += (size_t)G4H * K0CAT;   // 2048x832
    float* W1cat = p; p += (size_t)G4H * K1CAT;   // 2048x1024
    float* A0    = p; p += (size_t)B_ * K0CAT;    // 512x832
    float* A1    = p; p += (size_t)B_ * K1CAT;    // 512x1024
    float* gates = p; p += (size_t)B_ * G4H;      // 512x2048
    float* c0    = p; p += (size_t)B_ * H_;
    float* c1    = p; p += (size_t)B_ * H_;
    float* hs    = p; p += (size_t)B_ * T_ * H_;  // 8192x512, row = b*T + t

    // ---- setup (time-invariant) ----
    pack_w<<<(G4H * (K0CAT + K1CAT)) / 256, 256, 0, stream>>>(
        W_hh0, W_ih0, W_ih1, W_hh1, W0cat, W1cat);

    dim3 gq(H_ / BM, H_ / BN);            // 8x8
    gemm_tn<<<gq, 256, 0, stream>>>(fused, I_, W_in,   I_, ctx,   H_, I_, b_in,   nullptr, nullptr, 0);
    gemm_tn<<<gq, 256, 0, stream>>>(fused, I_, W_cell, I_, ccell, H_, I_, b_cell, nullptr, nullptr, 0);

    // context contribution to layer-0 gates + both biases (time-invariant)
    dim3 gg(B_ / BM, G4H / BN);           // 8x32
    gemm_tn<<<gg, 256, 0, stream>>>(ctx, H_, W_ih0 + E_, 812, ctxg, G4H, H_, b_ih0, b_hh0, nullptr, 0);

    init_state<<<(B_ * H_) / 256, 256, 0, stream>>>(ctx, ccell, A0, A1, c0, c1);

    // ---- recurrent loop ----
    for (int t = 0; t < T_; ++t) {
        pack_emb<<<(B_ * E_) / 256, 256, 0, stream>>>(emb, target, A0, t);
        gemm_tn<<<gg, 256, 0, stream>>>(A0, K0CAT, W0cat, K0CAT, gates, G4H, K0CAT,
                                        nullptr, nullptr, ctxg, G4H);
        lstm_cell0<<<(B_ * H_) / 256, 256, 0, stream>>>(gates, c0, A0, A1);
        gemm_tn<<<gg, 256, 0, stream>>>(A1, K1CAT, W1cat, K1CAT, gates, G4H, K1CAT,
                                        b_ih1, b_hh1, nullptr, 0);
        lstm_cell1<<<(B_ * H_) / 256, 256, 0, stream>>>(gates, c1, A1, hs, t);
    }

    // ---- output projection: logits[b*T+t][v] ----
    dim3 go((B_ * T_) / BM, V_ / BN);     // 128x125
    gemm_tn<<<go, 256, 0, stream>>>(hs, H_, W_out, H_, out, V_, H_, b_out, nullptr, nullptr, 0);
}

// Round 2
// 1373.652 us; speedup vs baseline: 2.0796x; 2.0796x over previous
//
#include <hip/hip_runtime.h>
#include <cstdint>

#define B_   512
#define I_   2560
#define H_   512
#define E_   300
#define V_   8000
#define VPAD 8064    // 63 * 128
#define T_   16
#define G4H  2048
#define SOS_ 2

#define K0CAT 832    // 512 (h0) + 300 (emb) + 20 pad
#define K1CAT 1024   // 512 (h0) + 512 (h1)

typedef _Float16 f16;
typedef _Float16 f16x8 __attribute__((ext_vector_type(8)));
typedef _Float16 f16x4 __attribute__((ext_vector_type(4)));
typedef float    f32x4 __attribute__((ext_vector_type(4)));

__device__ __forceinline__ float sigmoidf_(float x) {
    return 1.0f / (1.0f + __expf(-x));
}

__device__ __forceinline__ void gload16(const void* g, void* l) {
    __builtin_amdgcn_global_load_lds(
        (const __attribute__((address_space(1))) void*)g,
        (__attribute__((address_space(3))) void*)l,
        16, 0, 0);
}

// ---------------------------------------------------------------------------
// MFMA f16 GEMM: C[M,N] = A[M,K] @ B[N,K]^T (+bias1[n] +bias2[n] +Cadd[m,n])
// 128x128 tile, 256 threads = 4 waves (2x2), each wave 64x64 via 4x4 16x16x32
// fragments. BK=32. Linear LDS, global_load_lds width=16 (m97 structure).
// Requires M%128==0, K%32==0, B padded to N%128==0; stores guarded col<Nvalid.
// ---------------------------------------------------------------------------
__global__ __launch_bounds__(256)
void gemm_mfma(const f16* __restrict__ A, int lda,
               const f16* __restrict__ Bw, int ldb,
               float* __restrict__ C, int ldc,
               int K, int Nvalid,
               const float* __restrict__ bias1,
               const float* __restrict__ bias2,
               const float* __restrict__ Cadd, int ldadd)
{
    __shared__ f16 As[128][32];
    __shared__ f16 Bs[128][32];

    const int tid  = threadIdx.x;
    const int w    = tid >> 6;       // wave 0..3
    const int lane = tid & 63;
    const int bm   = blockIdx.x * 128;
    const int bn   = blockIdx.y * 128;
    const int wr   = w >> 1;         // wave row (0..1)
    const int wc   = w & 1;          // wave col (0..1)

    // staging: each wave issues 2 lines per matrix; line = 64 lanes x 16B = 16 rows
    const int srow = lane >> 2;          // 0..15
    const int skel = (lane & 3) * 8;     // f16 element offset in k

    const f16* Ag0 = A  + (size_t)(bm + w*32 +      srow) * lda + skel;
    const f16* Ag1 = A  + (size_t)(bm + w*32 + 16 + srow) * lda + skel;
    const f16* Bg0 = Bw + (size_t)(bn + w*32 +      srow) * ldb + skel;
    const f16* Bg1 = Bw + (size_t)(bn + w*32 + 16 + srow) * ldb + skel;
    f16* Al0 = &As[w*32     ][0];
    f16* Al1 = &As[w*32 + 16][0];
    f16* Bl0 = &Bs[w*32     ][0];
    f16* Bl1 = &Bs[w*32 + 16][0];

    // fragment reads: lane holds row/col (lane&15), k-slice (lane>>4)*8..+7
    const int frow = lane & 15;
    const int fk   = (lane >> 4) * 8;

    f32x4 acc[4][4] = {};

    for (int k0 = 0; k0 < K; k0 += 32) {
        gload16(Ag0 + k0, Al0);
        gload16(Ag1 + k0, Al1);
        gload16(Bg0 + k0, Bl0);
        gload16(Bg1 + k0, Bl1);
        __syncthreads();   // drains vmcnt -> tile resident

        f16x8 af[4], bf[4];
        #pragma unroll
        for (int m = 0; m < 4; ++m)
            af[m] = *reinterpret_cast<const f16x8*>(&As[wr*64 + m*16 + frow][fk]);
        #pragma unroll
        for (int n = 0; n < 4; ++n)
            bf[n] = *reinterpret_cast<const f16x8*>(&Bs[wc*64 + n*16 + frow][fk]);

        #pragma unroll
        for (int m = 0; m < 4; ++m)
            #pragma unroll
            for (int n = 0; n < 4; ++n)
                acc[m][n] = __builtin_amdgcn_mfma_f32_16x16x32_f16(
                    af[m], bf[n], acc[m][n], 0, 0, 0);

        __syncthreads();   // all reads done before next overwrite
    }

    // epilogue: D row = (lane>>4)*4 + reg, col = lane&15  (m89-verified)
    const int rowb = bm + wr*64 + (lane >> 4) * 4;
    #pragma unroll
    for (int n = 0; n < 4; ++n) {
        const int col = bn + wc*64 + n*16 + frow;
        if (col >= Nvalid) continue;
        float badd = 0.0f;
        if (bias1) badd += bias1[col];
        if (bias2) badd += bias2[col];
        #pragma unroll
        for (int m = 0; m < 4; ++m) {
            const int r0 = rowb + m*16;
            #pragma unroll
            for (int r = 0; r < 4; ++r) {
                float v = acc[m][n][r] + badd;
                if (Cadd) v += Cadd[(size_t)(r0 + r) * ldadd + col];
                C[(size_t)(r0 + r) * ldc + col] = v;
            }
        }
    }
}

// ---------------------------------------------------------------------------
// fp32 -> f16 convert, 4 elems/thread (n must be multiple of 1024)
// ---------------------------------------------------------------------------
__global__ __launch_bounds__(256)
void conv_f16_k(const float* __restrict__ src, f16* __restrict__ dst)
{
    const int i = blockIdx.x * 256 + threadIdx.x;
    const float4 v = reinterpret_cast<const float4*>(src)[i];
    f16x4 h = { (f16)v.x, (f16)v.y, (f16)v.z, (f16)v.w };
    *reinterpret_cast<f16x4*>(dst + (size_t)i * 4) = h;
}

// ---------------------------------------------------------------------------
// Weight packs (one-time)
// ---------------------------------------------------------------------------
__global__ __launch_bounds__(256)
void pack_w0(const float* __restrict__ Whh0, const float* __restrict__ Wih0,
             f16* __restrict__ W0)
{
    const int idx = blockIdx.x * 256 + threadIdx.x;   // 2048*832
    const int g = idx / K0CAT, k = idx % K0CAT;
    float v;
    if (k < 512)      v = Whh0[(size_t)g * 512 + k];
    else if (k < 812) v = Wih0[(size_t)g * 812 + (k - 512)];
    else              v = 0.0f;
    W0[idx] = (f16)v;
}

__global__ __launch_bounds__(256)
void pack_w1(const float* __restrict__ Wih1, const float* __restrict__ Whh1,
             f16* __restrict__ W1)
{
    const int idx = blockIdx.x * 256 + threadIdx.x;   // 2048*1024
    const int g = idx >> 10, k = idx & 1023;
    const float v = (k < 512) ? Wih1[(size_t)g * 512 + k]
                              : Whh1[(size_t)g * 512 + (k - 512)];
    W1[idx] = (f16)v;
}

__global__ __launch_bounds__(256)
void pack_wctx(const float* __restrict__ Wih0, f16* __restrict__ Wc)
{
    const int idx = blockIdx.x * 256 + threadIdx.x;   // 2048*512
    const int g = idx >> 9, k = idx & 511;
    Wc[idx] = (f16)Wih0[(size_t)g * 812 + 300 + k];
}

__global__ __launch_bounds__(256)
void pack_wout(const float* __restrict__ Wout, f16* __restrict__ Wo)
{
    const int idx = blockIdx.x * 256 + threadIdx.x;   // 8064*512
    const int r = idx >> 9, k = idx & 511;
    Wo[idx] = (r < V_) ? (f16)Wout[(size_t)r * 512 + k] : (f16)0.0f;
}

// ---------------------------------------------------------------------------
// Init: A0[:, :512]=ctx, A0[:,512:812]=emb[SOS], A0[:,812:832]=0,
//       A1[:,512:]=ctx (h1 init), ctx16=f16(ctx), c0=c1=ccell
// ---------------------------------------------------------------------------
__global__ __launch_bounds__(256)
void init_state(const float* __restrict__ ctx, const float* __restrict__ ccell,
                const float* __restrict__ emb,
                f16* __restrict__ A0, f16* __restrict__ A1,
                f16* __restrict__ ctx16,
                float* __restrict__ c0, float* __restrict__ c1)
{
    const int idx = blockIdx.x * 256 + threadIdx.x;   // 512*512
    const int b = idx >> 9, h = idx & 511;
    const f16 ch = (f16)ctx[idx];
    A0[(size_t)b * K0CAT + h] = ch;
    A1[(size_t)b * K1CAT + 512 + h] = ch;
    ctx16[idx] = ch;
    const float cc = ccell[idx];
    c0[idx] = cc;
    c1[idx] = cc;
    if (h < 20)  A0[(size_t)b * K0CAT + 812 + h] = (f16)0.0f;
    if (h < E_)  A0[(size_t)b * K0CAT + 512 + h] = (f16)emb[SOS_ * E_ + h];
}

// ---------------------------------------------------------------------------
// LSTM cell layer 0: update c0, h0 -> A0[:, :512], A1[:, :512]
// ---------------------------------------------------------------------------
__global__ __launch_bounds__(256)
void lstm_cell0(const float* __restrict__ gates, float* __restrict__ c0,
                f16* __restrict__ A0, f16* __restrict__ A1)
{
    const int idx = blockIdx.x * 256 + threadIdx.x;
    const int b = idx >> 9, h = idx & 511;
    const float* gr = gates + (size_t)b * G4H;
    const float gi = gr[h], gf = gr[512 + h], gg = gr[1024 + h], go = gr[1536 + h];
    const float c = c0[idx];
    const float cn = sigmoidf_(gf) * c + sigmoidf_(gi) * tanhf(gg);
    const float hn = sigmoidf_(go) * tanhf(cn);
    c0[idx] = cn;
    const f16 hh = (f16)hn;
    A0[(size_t)b * K0CAT + h] = hh;
    A1[(size_t)b * K1CAT + h] = hh;
}

// ---------------------------------------------------------------------------
// LSTM cell layer 1: update c1, h1 -> A1[:,512:], hs; also pre-gather the
// step-(t+1) embedding into A0[:, 512:812]
// ---------------------------------------------------------------------------
__global__ __launch_bounds__(256)
void lstm_cell1(const float* __restrict__ gates, float* __restrict__ c1,
                f16* __restrict__ A1, f16* __restrict__ hs,
                const float* __restrict__ emb, const int* __restrict__ target,
                f16* __restrict__ A0, int t)
{
    const int idx = blockIdx.x * 256 + threadIdx.x;
    const int b = idx >> 9, h = idx & 511;
    const float* gr = gates + (size_t)b * G4H;
    const float gi = gr[h], gf = gr[512 + h], gg = gr[1024 + h], go = gr[1536 + h];
    const float c = c1[idx];
    const float cn = sigmoidf_(gf) * c + sigmoidf_(gi) * tanhf(gg);
    const float hn = sigmoidf_(go) * tanhf(cn);
    c1[idx] = cn;
    const f16 hh = (f16)hn;
    A1[(size_t)b * K1CAT + 512 + h] = hh;
    hs[((size_t)b * T_ + t) * H_ + h] = hh;
    if (h < E_ && t + 1 < T_) {
        const int wd = target[b * T_ + t];   // input word for step t+1
        A0[(size_t)b * K0CAT + 512 + h] = (f16)emb[(size_t)wd * E_ + h];
    }
}

// ---------------------------------------------------------------------------
extern "C" void kernel_launch(void* const* d_in, const int* in_sizes, int n_in,
                              void* d_out, int out_size, void* d_ws, size_t ws_size,
                              hipStream_t stream)
{
    const float* fused  = (const float*)d_in[0];
    const int*   target = (const int*)d_in[1];
    const float* emb    = (const float*)d_in[3];
    const float* W_in   = (const float*)d_in[4];
    const float* b_in   = (const float*)d_in[5];
    const float* W_cell = (const float*)d_in[6];
    const float* b_cell = (const float*)d_in[7];
    const float* W_ih0  = (const float*)d_in[8];
    const float* W_hh0  = (const float*)d_in[9];
    const float* b_ih0  = (const float*)d_in[10];
    const float* b_hh0  = (const float*)d_in[11];
    const float* W_ih1  = (const float*)d_in[12];
    const float* W_hh1  = (const float*)d_in[13];
    const float* b_ih1  = (const float*)d_in[14];
    const float* b_hh1  = (const float*)d_in[15];
    const float* W_out  = (const float*)d_in[16];
    const float* b_out  = (const float*)d_in[17];
    float* out = (float*)d_out;

    char* p = (char*)d_ws;
    auto carve = [&](size_t bytes) {
        char* r = p;
        p += (bytes + 255) & ~(size_t)255;
        return r;
    };
    float* ctx    = (float*)carve((size_t)B_ * H_ * 4);
    float* ccell  = (float*)carve((size_t)B_ * H_ * 4);
    float* ctxg   = (float*)carve((size_t)B_ * G4H * 4);
    float* gates  = (float*)carve((size_t)B_ * G4H * 4);
    float* c0     = (float*)carve((size_t)B_ * H_ * 4);
    float* c1     = (float*)carve((size_t)B_ * H_ * 4);
    f16* fused16  = (f16*)carve((size_t)B_ * I_ * 2);
    f16* Win16    = (f16*)carve((size_t)H_ * I_ * 2);
    f16* Wcell16  = (f16*)carve((size_t)H_ * I_ * 2);
    f16* W0       = (f16*)carve((size_t)G4H * K0CAT * 2);
    f16* W1       = (f16*)carve((size_t)G4H * K1CAT * 2);
    f16* Wctx     = (f16*)carve((size_t)G4H * H_ * 2);
    f16* Wout16   = (f16*)carve((size_t)VPAD * H_ * 2);
    f16* ctx16    = (f16*)carve((size_t)B_ * H_ * 2);
    f16* A0       = (f16*)carve((size_t)B_ * K0CAT * 2);
    f16* A1       = (f16*)carve((size_t)B_ * K1CAT * 2);
    f16* hs       = (f16*)carve((size_t)B_ * T_ * H_ * 2);

    // ---- one-time converts / packs ----
    conv_f16_k<<<(B_ * I_) / 1024, 256, 0, stream>>>(fused, fused16);
    conv_f16_k<<<(H_ * I_) / 1024, 256, 0, stream>>>(W_in, Win16);
    conv_f16_k<<<(H_ * I_) / 1024, 256, 0, stream>>>(W_cell, Wcell16);
    pack_w0  <<<(G4H * K0CAT) / 256, 256, 0, stream>>>(W_hh0, W_ih0, W0);
    pack_w1  <<<(G4H * K1CAT) / 256, 256, 0, stream>>>(W_ih1, W_hh1, W1);
    pack_wctx<<<(G4H * H_)    / 256, 256, 0, stream>>>(W_ih0, Wctx);
    pack_wout<<<(VPAD * H_)   / 256, 256, 0, stream>>>(W_out, Wout16);

    // ---- context / cell-init projections ----
    gemm_mfma<<<dim3(B_/128, H_/128), 256, 0, stream>>>(
        fused16, I_, Win16, I_, ctx, H_, I_, H_, b_in, nullptr, nullptr, 0);
    gemm_mfma<<<dim3(B_/128, H_/128), 256, 0, stream>>>(
        fused16, I_, Wcell16, I_, ccell, H_, I_, H_, b_cell, nullptr, nullptr, 0);

    init_state<<<(B_ * H_) / 256, 256, 0, stream>>>(ctx, ccell, emb, A0, A1, ctx16, c0, c1);

    // time-invariant context contribution to layer-0 gates (+ both biases)
    gemm_mfma<<<dim3(B_/128, G4H/128), 256, 0, stream>>>(
        ctx16, H_, Wctx, H_, ctxg, G4H, H_, G4H, b_ih0, b_hh0, nullptr, 0);

    // ---- recurrent loop ----
    for (int t = 0; t < T_; ++t) {
        gemm_mfma<<<dim3(B_/128, G4H/128), 256, 0, stream>>>(
            A0, K0CAT, W0, K0CAT, gates, G4H, K0CAT, G4H,
            nullptr, nullptr, ctxg, G4H);
        lstm_cell0<<<(B_ * H_) / 256, 256, 0, stream>>>(gates, c0, A0, A1);
        gemm_mfma<<<dim3(B_/128, G4H/128), 256, 0, stream>>>(
            A1, K1CAT, W1, K1CAT, gates, G4H, K1CAT, G4H,
            b_ih1, b_hh1, nullptr, 0);
        lstm_cell1<<<(B_ * H_) / 256, 256, 0, stream>>>(
            gates, c1, A1, hs, emb, target, A0, t);
    }

    // ---- output projection ----
    gemm_mfma<<<dim3((B_ * T_) / 128, VPAD / 128), 256, 0, stream>>>(
        hs, H_, Wout16, H_, out, V_, H_, V_, b_out, nullptr, nullptr, 0);
}

// Round 3
// 834.587 us; speedup vs baseline: 3.4228x; 1.6459x over previous
//
#include <hip/hip_runtime.h>
#include <cstdint>

#define B_   512
#define I_   2560
#define H_   512
#define E_   300
#define EW   320     // padded emb width
#define V_   8000
#define VPAD 8064    // 63 * 128
#define T_   16
#define G4H  2048
#define SOS_ 2

typedef _Float16 f16;
typedef _Float16 f16x8 __attribute__((ext_vector_type(8)));
typedef _Float16 f16x4 __attribute__((ext_vector_type(4)));
typedef float    f32x4 __attribute__((ext_vector_type(4)));

__device__ __forceinline__ float sigmoidf_(float x) {
    return 1.0f / (1.0f + __expf(-x));
}

__device__ __forceinline__ void gload16(const void* g, void* l) {
    __builtin_amdgcn_global_load_lds(
        (const __attribute__((address_space(1))) void*)g,
        (__attribute__((address_space(3))) void*)l,
        16, 0, 0);
}

// ---------------------------------------------------------------------------
// Generic MFMA f16 GEMM (m97 structure, validated round 2): 128x128 tile,
// BK=32, 4 waves 2x2, linear LDS + global_load_lds w=16.
// ---------------------------------------------------------------------------
__global__ __launch_bounds__(256)
void gemm_mfma(const f16* __restrict__ A, int lda,
               const f16* __restrict__ Bw, int ldb,
               float* __restrict__ C, int ldc,
               int K, int Nvalid,
               const float* __restrict__ bias1,
               const float* __restrict__ bias2,
               const float* __restrict__ Cadd, int ldadd)
{
    __shared__ f16 As[128][32];
    __shared__ f16 Bs[128][32];

    const int tid  = threadIdx.x;
    const int w    = tid >> 6;
    const int lane = tid & 63;
    const int bm   = blockIdx.x * 128;
    const int bn   = blockIdx.y * 128;
    const int wr   = w >> 1;
    const int wc   = w & 1;

    const int srow = lane >> 2;
    const int skel = (lane & 3) * 8;

    const f16* Ag0 = A  + (size_t)(bm + w*32 +      srow) * lda + skel;
    const f16* Ag1 = A  + (size_t)(bm + w*32 + 16 + srow) * lda + skel;
    const f16* Bg0 = Bw + (size_t)(bn + w*32 +      srow) * ldb + skel;
    const f16* Bg1 = Bw + (size_t)(bn + w*32 + 16 + srow) * ldb + skel;
    f16* Al0 = &As[w*32     ][0];
    f16* Al1 = &As[w*32 + 16][0];
    f16* Bl0 = &Bs[w*32     ][0];
    f16* Bl1 = &Bs[w*32 + 16][0];

    const int frow = lane & 15;
    const int fk   = (lane >> 4) * 8;

    f32x4 acc[4][4] = {};

    for (int k0 = 0; k0 < K; k0 += 32) {
        gload16(Ag0 + k0, Al0);
        gload16(Ag1 + k0, Al1);
        gload16(Bg0 + k0, Bl0);
        gload16(Bg1 + k0, Bl1);
        __syncthreads();

        f16x8 af[4], bf[4];
        #pragma unroll
        for (int m = 0; m < 4; ++m)
            af[m] = *reinterpret_cast<const f16x8*>(&As[wr*64 + m*16 + frow][fk]);
        #pragma unroll
        for (int n = 0; n < 4; ++n)
            bf[n] = *reinterpret_cast<const f16x8*>(&Bs[wc*64 + n*16 + frow][fk]);

        #pragma unroll
        for (int m = 0; m < 4; ++m)
            #pragma unroll
            for (int n = 0; n < 4; ++n)
                acc[m][n] = __builtin_amdgcn_mfma_f32_16x16x32_f16(
                    af[m], bf[n], acc[m][n], 0, 0, 0);

        __syncthreads();
    }

    const int rowb = bm + wr*64 + (lane >> 4) * 4;
    #pragma unroll
    for (int n = 0; n < 4; ++n) {
        const int col = bn + wc*64 + n*16 + frow;
        if (col >= Nvalid) continue;
        float badd = 0.0f;
        if (bias1) badd += bias1[col];
        if (bias2) badd += bias2[col];
        #pragma unroll
        for (int m = 0; m < 4; ++m) {
            const int r0 = rowb + m*16;
            #pragma unroll
            for (int r = 0; r < 4; ++r) {
                float v = acc[m][n][r] + badd;
                if (Cadd) v += Cadd[(size_t)(r0 + r) * ldadd + col];
                C[(size_t)(r0 + r) * ldc + col] = v;
            }
        }
    }
}

// ---------------------------------------------------------------------------
// Recurrent-step GEMM + fused LSTM cell.
// C[512, 2048(packed)] = A @ Wp^T, A row = [Ap1 row (k<512) | Ap2 row (k>=512)].
// Packed cols: col = (h>>5)*128 + g*32 + (h&31), gate order i,f,g,o.
// BM=64 BN=128 BK=64, 4 waves (2x2, wave=32x64), double-buffered staging with
// XOR-preswizzled global_load_lds source (linear LDS dest + swizzled read).
// Epilogue: gates -> LDS[64][132] f32 -> in-block cell update -> h (f16).
// ---------------------------------------------------------------------------
__global__ __launch_bounds__(256)
void gemm_step(const f16* __restrict__ Ap1, const f16* __restrict__ Ap2, int lda2,
               const f16* __restrict__ Wp, int K,
               const float* __restrict__ Cadd,           // ctxg (packed) or null
               const float* __restrict__ bih, const float* __restrict__ bhh,
               float* __restrict__ cst,
               f16* __restrict__ hout1,
               f16* __restrict__ hout2, int h2stride)
{
    __shared__ uint4 smem4[49152 / 16];
    char* smem = (char*)smem4;
    // layout: [0,8K) As buf0, [8K,16K) As buf1, [16K,32K) Bs buf0, [32K,48K) Bs buf1
    // epilogue aliases [0,33.8K) as float gates[64][132]

    const int tid  = threadIdx.x;
    const int w    = tid >> 6;
    const int lane = tid & 63;
    const int bm   = blockIdx.x * 64;
    const int bn   = blockIdx.y * 128;
    const int wr   = w >> 1, wc = w & 1;
    const int frow = lane & 15, hi = lane >> 4;
    const int sw   = (frow & 7) << 4;                       // read-side swizzle
    const int srow8 = lane >> 3;                            // staging row-in-line
    const int ksb  = ((((lane & 7) * 16) ^ (srow8 << 4)) >> 1);  // preswizzled k (f16)

    const int NT = K >> 6;
    f32x4 acc[2][4] = {};

    auto stage = [&](int bsel, int kt) {
        const int k0 = kt << 6;
        #pragma unroll
        for (int j = 0; j < 2; ++j) {                       // A: 2 lines/wave
            const int row = w*16 + j*8 + srow8;
            const f16* src;
            if (k0 < 512) src = Ap1 + (size_t)(bm + row) * 512  + k0 + ksb;
            else          src = Ap2 + (size_t)(bm + row) * lda2 + (k0 - 512) + ksb;
            gload16(src, smem + bsel*8192 + (w*2 + j)*1024 + lane*16);
        }
        #pragma unroll
        for (int j = 0; j < 4; ++j) {                       // B: 4 lines/wave
            const int row = w*32 + j*8 + srow8;
            gload16(Wp + (size_t)(bn + row) * K + k0 + ksb,
                    smem + 16384 + bsel*16384 + (w*4 + j)*1024 + lane*16);
        }
    };

    auto compute = [&](int bsel) {
        const char* As = smem + bsel*8192;
        const char* Bs = smem + 16384 + bsel*16384;
        #pragma unroll
        for (int ks = 0; ks < 2; ++ks) {
            const int cb = (ks*64 + hi*16) ^ sw;
            f16x8 af[2], bf[4];
            #pragma unroll
            for (int m = 0; m < 2; ++m)
                af[m] = *reinterpret_cast<const f16x8*>(As + (wr*32 + m*16 + frow)*128 + cb);
            #pragma unroll
            for (int n = 0; n < 4; ++n)
                bf[n] = *reinterpret_cast<const f16x8*>(Bs + (wc*64 + n*16 + frow)*128 + cb);
            #pragma unroll
            for (int m = 0; m < 2; ++m)
                #pragma unroll
                for (int n = 0; n < 4; ++n)
                    acc[m][n] = __builtin_amdgcn_mfma_f32_16x16x32_f16(
                        af[m], bf[n], acc[m][n], 0, 0, 0);
        }
    };

    stage(0, 0);
    __syncthreads();
    int buf = 0;
    for (int kt = 0; kt + 1 < NT; ++kt) {
        stage(buf ^ 1, kt + 1);     // prefetch next tile (latency hides under compute)
        compute(buf);
        __syncthreads();            // drains vmcnt -> next tile resident
        buf ^= 1;
    }
    compute(buf);
    __syncthreads();                // all LDS reads done; safe to alias as gates

    // gates -> LDS (+ Cadd), f32 [64][132]
    float* gs = (float*)smem;
    #pragma unroll
    for (int m = 0; m < 2; ++m) {
        const int row = wr*32 + m*16 + hi*4;
        #pragma unroll
        for (int n = 0; n < 4; ++n) {
            const int col = wc*64 + n*16 + frow;
            #pragma unroll
            for (int r = 0; r < 4; ++r) {
                float v = acc[m][n][r];
                if (Cadd) v += Cadd[(size_t)(bm + row + r) * G4H + bn + col];
                gs[(row + r)*132 + col] = v;
            }
        }
    }
    __syncthreads();

    // cell update: thread -> h' = tid&31, rows (tid>>5)*8 .. +8
    const int hp = tid & 31;
    const int hg = blockIdx.y * 32 + hp;
    float bi0 = 0.f, bi1 = 0.f, bi2 = 0.f, bi3 = 0.f;
    if (bih) {
        bi0 = bih[hg]        + bhh[hg];
        bi1 = bih[512 + hg]  + bhh[512 + hg];
        bi2 = bih[1024 + hg] + bhh[1024 + hg];
        bi3 = bih[1536 + hg] + bhh[1536 + hg];
    }
    #pragma unroll
    for (int i = 0; i < 8; ++i) {
        const int r = (tid >> 5) * 8 + i;
        const int b = bm + r;
        const float gi = gs[r*132 +      hp] + bi0;
        const float gf = gs[r*132 + 32 + hp] + bi1;
        const float gc = gs[r*132 + 64 + hp] + bi2;
        const float go = gs[r*132 + 96 + hp] + bi3;
        const float c  = cst[(size_t)b * 512 + hg];
        const float cn = sigmoidf_(gf) * c + sigmoidf_(gi) * tanhf(gc);
        const float hn = sigmoidf_(go) * tanhf(cn);
        cst[(size_t)b * 512 + hg] = cn;
        hout1[(size_t)b * 512 + hg] = (f16)hn;
        if (hout2) hout2[(size_t)b * h2stride + hg] = (f16)hn;
    }
}

// ---------------------------------------------------------------------------
// One-time packs / converts
// ---------------------------------------------------------------------------
__global__ __launch_bounds__(256)
void conv_f16_k(const float* __restrict__ src, f16* __restrict__ dst)
{
    const int i = blockIdx.x * 256 + threadIdx.x;
    const float4 v = reinterpret_cast<const float4*>(src)[i];
    f16x4 h = { (f16)v.x, (f16)v.y, (f16)v.z, (f16)v.w };
    *reinterpret_cast<f16x4*>(dst + (size_t)i * 4) = h;
}

__global__ __launch_bounds__(256)
void pack_wincell(const float* __restrict__ Win, const float* __restrict__ Wcell,
                  f16* __restrict__ dst)
{
    const int i = blockIdx.x * 256 + threadIdx.x;   // 1024*2560/4
    const int r = i / 640, c4 = (i % 640) * 4;
    const float* src = (r < 512) ? Win + (size_t)r * I_ + c4
                                 : Wcell + (size_t)(r - 512) * I_ + c4;
    const float4 v = *reinterpret_cast<const float4*>(src);
    f16x4 h = { (f16)v.x, (f16)v.y, (f16)v.z, (f16)v.w };
    *reinterpret_cast<f16x4*>(dst + (size_t)i * 4) = h;
}

// packed row rp -> (g, h): g = (rp>>5)&3, h = (rp>>7)*32 + (rp&31)
__global__ __launch_bounds__(256)
void pack_w0p(const float* __restrict__ Whh0, const float* __restrict__ Wih0,
              f16* __restrict__ W0)
{
    const int idx = blockIdx.x * 256 + threadIdx.x;   // 2048*832
    const int rp = idx / 832, k = idx % 832;
    const int g = (rp >> 5) & 3, h = (rp >> 7) * 32 + (rp & 31);
    const int srow = g * 512 + h;
    float v;
    if (k < 512)      v = Whh0[(size_t)srow * 512 + k];
    else if (k < 812) v = Wih0[(size_t)srow * 812 + (k - 512)];
    else              v = 0.0f;
    W0[idx] = (f16)v;
}

__global__ __launch_bounds__(256)
void pack_w1p(const float* __restrict__ Wih1, const float* __restrict__ Whh1,
              f16* __restrict__ W1)
{
    const int idx = blockIdx.x * 256 + threadIdx.x;   // 2048*1024
    const int rp = idx >> 10, k = idx & 1023;
    const int g = (rp >> 5) & 3, h = (rp >> 7) * 32 + (rp & 31);
    const int srow = g * 512 + h;
    const float v = (k < 512) ? Wih1[(size_t)srow * 512 + k]
                              : Whh1[(size_t)srow * 512 + (k - 512)];
    W1[idx] = (f16)v;
}

__global__ __launch_bounds__(256)
void pack_wctxp(const float* __restrict__ Wih0, f16* __restrict__ Wc)
{
    const int idx = blockIdx.x * 256 + threadIdx.x;   // 2048*512
    const int rp = idx >> 9, k = idx & 511;
    const int g = (rp >> 5) & 3, h = (rp >> 7) * 32 + (rp & 31);
    Wc[idx] = (f16)Wih0[(size_t)(g * 512 + h) * 812 + 300 + k];
}

__global__ __launch_bounds__(256)
void pack_b0(const float* __restrict__ bih0, const float* __restrict__ bhh0,
             float* __restrict__ b01p)
{
    const int idx = blockIdx.x * 256 + threadIdx.x;   // 2048
    const int g = (idx >> 5) & 3, h = (idx >> 7) * 32 + (idx & 31);
    b01p[idx] = bih0[g * 512 + h] + bhh0[g * 512 + h];
}

__global__ __launch_bounds__(256)
void pack_wout(const float* __restrict__ Wout, f16* __restrict__ Wo)
{
    const int i = blockIdx.x * 256 + threadIdx.x;     // 8064*512/4
    const int r = i >> 7, c4 = (i & 127) * 4;
    f16x4 h = { (f16)0.f, (f16)0.f, (f16)0.f, (f16)0.f };
    if (r < V_) {
        const float4 v = *reinterpret_cast<const float4*>(Wout + (size_t)r * H_ + c4);
        h = f16x4{ (f16)v.x, (f16)v.y, (f16)v.z, (f16)v.w };
    }
    *reinterpret_cast<f16x4*>(Wo + (size_t)i * 4) = h;
}

// embAll[t][b][0:320] : e<300 -> emb[word(t,b)][e], else 0
__global__ __launch_bounds__(256)
void pack_emb_all(const float* __restrict__ emb, const int* __restrict__ target,
                  f16* __restrict__ embAll)
{
    const int idx = blockIdx.x * 256 + threadIdx.x;   // 16*512*320
    const int t = idx / (B_ * EW);
    const int rem = idx % (B_ * EW);
    const int b = rem / EW, e = rem % EW;
    const int wd = (t == 0) ? SOS_ : target[b * T_ + (t - 1)];
    const float v = (e < E_) ? emb[(size_t)wd * E_ + e] : 0.0f;
    embAll[idx] = (f16)v;
}

// ctx = ctxcc[:, :512] + b_in ; ccell = ctxcc[:, 512:] + b_cell
// writes ctx16, h0[0], h1[0] (f16), c0, c1 (f32)
__global__ __launch_bounds__(256)
void init_state(const float* __restrict__ ctxcc,
                const float* __restrict__ b_in, const float* __restrict__ b_cell,
                f16* __restrict__ ctx16, f16* __restrict__ h0, f16* __restrict__ h1,
                float* __restrict__ c0, float* __restrict__ c1)
{
    const int idx = blockIdx.x * 256 + threadIdx.x;   // 512*512
    const int b = idx >> 9, h = idx & 511;
    const float cv = ctxcc[(size_t)b * 1024 + h] + b_in[h];
    const float cc = ctxcc[(size_t)b * 1024 + 512 + h] + b_cell[h];
    const f16 ch = (f16)cv;
    ctx16[idx] = ch;
    h0[idx] = ch;
    h1[idx] = ch;
    c0[idx] = cc;
    c1[idx] = cc;
}

// ---------------------------------------------------------------------------
extern "C" void kernel_launch(void* const* d_in, const int* in_sizes, int n_in,
                              void* d_out, int out_size, void* d_ws, size_t ws_size,
                              hipStream_t stream)
{
    const float* fused  = (const float*)d_in[0];
    const int*   target = (const int*)d_in[1];
    const float* emb    = (const float*)d_in[3];
    const float* W_in   = (const float*)d_in[4];
    const float* b_in   = (const float*)d_in[5];
    const float* W_cell = (const float*)d_in[6];
    const float* b_cell = (const float*)d_in[7];
    const float* W_ih0  = (const float*)d_in[8];
    const float* W_hh0  = (const float*)d_in[9];
    const float* b_ih0  = (const float*)d_in[10];
    const float* b_hh0  = (const float*)d_in[11];
    const float* W_ih1  = (const float*)d_in[12];
    const float* W_hh1  = (const float*)d_in[13];
    const float* b_ih1  = (const float*)d_in[14];
    const float* b_hh1  = (const float*)d_in[15];
    const float* W_out  = (const float*)d_in[16];
    const float* b_out  = (const float*)d_in[17];
    float* out = (float*)d_out;

    char* p = (char*)d_ws;
    auto carve = [&](size_t bytes) {
        char* r = p;
        p += (bytes + 255) & ~(size_t)255;
        return r;
    };
    float* ctxcc  = (float*)carve((size_t)B_ * 1024 * 4);
    float* ctxg   = (float*)carve((size_t)B_ * G4H * 4);
    float* b01p   = (float*)carve((size_t)G4H * 4);
    float* c0     = (float*)carve((size_t)B_ * H_ * 4);
    float* c1     = (float*)carve((size_t)B_ * H_ * 4);
    f16* fused16  = (f16*)carve((size_t)B_ * I_ * 2);
    f16* WinCell  = (f16*)carve((size_t)1024 * I_ * 2);
    f16* W0p      = (f16*)carve((size_t)G4H * 832 * 2);
    f16* W1p      = (f16*)carve((size_t)G4H * 1024 * 2);
    f16* Wctxp    = (f16*)carve((size_t)G4H * H_ * 2);
    f16* Wout16   = (f16*)carve((size_t)VPAD * H_ * 2);
    f16* ctx16    = (f16*)carve((size_t)B_ * H_ * 2);
    f16* h0a      = (f16*)carve((size_t)B_ * H_ * 2);
    f16* h0b      = (f16*)carve((size_t)B_ * H_ * 2);
    f16* h1a      = (f16*)carve((size_t)B_ * H_ * 2);
    f16* h1b      = (f16*)carve((size_t)B_ * H_ * 2);
    f16* embAll   = (f16*)carve((size_t)T_ * B_ * EW * 2);
    f16* hs       = (f16*)carve((size_t)B_ * T_ * H_ * 2);

    // ---- one-time packs ----
    conv_f16_k  <<<(B_ * I_) / 1024, 256, 0, stream>>>(fused, fused16);
    pack_wincell<<<(1024 * I_) / 1024, 256, 0, stream>>>(W_in, W_cell, WinCell);
    pack_w0p    <<<(G4H * 832) / 256, 256, 0, stream>>>(W_hh0, W_ih0, W0p);
    pack_w1p    <<<(G4H * 1024) / 256, 256, 0, stream>>>(W_ih1, W_hh1, W1p);
    pack_wctxp  <<<(G4H * H_) / 256, 256, 0, stream>>>(W_ih0, Wctxp);
    pack_b0     <<<G4H / 256, 256, 0, stream>>>(b_ih0, b_hh0, b01p);
    pack_wout   <<<(VPAD * H_) / 1024, 256, 0, stream>>>(W_out, Wout16);
    pack_emb_all<<<(T_ * B_ * EW) / 256, 256, 0, stream>>>(emb, target, embAll);

    // ---- ctx / ccell in one GEMM: [512,1024] = fused16 @ [Win|Wcell]^T ----
    gemm_mfma<<<dim3(B_/128, 1024/128), 256, 0, stream>>>(
        fused16, I_, WinCell, I_, ctxcc, 1024, I_, 1024,
        nullptr, nullptr, nullptr, 0);

    init_state<<<(B_ * H_) / 256, 256, 0, stream>>>(
        ctxcc, b_in, b_cell, ctx16, h0a, h1a, c0, c1);

    // ---- time-invariant ctx gate contribution (packed cols, + biases) ----
    gemm_mfma<<<dim3(B_/128, G4H/128), 256, 0, stream>>>(
        ctx16, H_, Wctxp, H_, ctxg, G4H, H_, G4H,
        b01p, nullptr, nullptr, 0);

    // ---- recurrent loop: 2 fused GEMM+cell kernels per step ----
    f16* h0buf[2] = { h0a, h0b };
    f16* h1buf[2] = { h1a, h1b };
    for (int t = 0; t < T_; ++t) {
        f16* h0in  = h0buf[t & 1];
        f16* h0out = h0buf[(t + 1) & 1];
        f16* h1in  = h1buf[t & 1];
        f16* h1out = h1buf[(t + 1) & 1];
        gemm_step<<<dim3(B_/64, G4H/128), 256, 0, stream>>>(
            h0in, embAll + (size_t)t * B_ * EW, EW, W0p, 832,
            ctxg, nullptr, nullptr, c0, h0out, nullptr, 0);
        gemm_step<<<dim3(B_/64, G4H/128), 256, 0, stream>>>(
            h0out, h1in, 512, W1p, 1024,
            nullptr, b_ih1, b_hh1, c1, h1out, hs + (size_t)t * H_, T_ * H_);
    }

    // ---- output projection ----
    gemm_mfma<<<dim3((B_ * T_) / 128, VPAD / 128), 256, 0, stream>>>(
        hs, H_, Wout16, H_, out, V_, H_, V_, b_out, nullptr, nullptr, 0);
}